// Round 1
// baseline (730.002 us; speedup 1.0000x reference)
//
#include <hip/hip_runtime.h>
#include <hip/hip_bf16.h>

#define DEPTH   8
#define NNODES  87381   // (4^9-1)/3
#define KIN     640     // E + A*H
#define NOUTS   896     // 3H + A*H

typedef __attribute__((ext_vector_type(8))) unsigned short ushort8;
typedef __attribute__((ext_vector_type(8))) __bf16        bf16x8;
typedef __attribute__((ext_vector_type(4))) float         f32x4;

union Frag8 { ushort8 u; bf16x8 b; };

__device__ __forceinline__ unsigned short f2bf(float f) {
    unsigned int x = __float_as_uint(f);
    x += 0x7fffu + ((x >> 16) & 1u);          // round-to-nearest-even
    return (unsigned short)(x >> 16);
}
__device__ __forceinline__ float sigf(float x) { return 1.0f / (1.0f + __expf(-x)); }
__device__ __forceinline__ float tanh_fast(float x) { return 2.0f * sigf(2.0f * x) - 1.0f; }

// Pack Wc[896][640] bf16 = [[W_iou | U_iou], [W_f (row d=o2&127) | U_f]]
__global__ __launch_bounds__(256) void build_wc(
    const float* __restrict__ W_iou, const float* __restrict__ U_iou,
    const float* __restrict__ W_f,   const float* __restrict__ U_f,
    unsigned short* __restrict__ Wc)
{
    int idx = blockIdx.x * 256 + threadIdx.x;          // 0 .. 896*640-1
    int out = idx / KIN;
    int k   = idx - out * KIN;
    float v;
    if (out < 384) {
        v = (k < 128) ? W_iou[out * 128 + k] : U_iou[out * 512 + (k - 128)];
    } else {
        int o2 = out - 384;
        v = (k < 128) ? W_f[(o2 & 127) * 128 + k] : U_f[o2 * 512 + (k - 128)];
    }
    Wc[idx] = f2bf(v);
}

// One tree level, fused GEMM + LSTM cell.
// Block: 512 threads (8 waves), BM=64 nodes. Wave w owns cols {c*128 + w*16 .. +15}, c=0..6.
__global__ __launch_bounds__(512) void tree_level(
    const float* __restrict__ emb,
    const unsigned short* __restrict__ Wc,
    const float* __restrict__ b_iou, const float* __restrict__ b_uiou,
    const float* __restrict__ b_wf,  const float* __restrict__ b_uf,
    const float* __restrict__ h0,    const float* __restrict__ c0,
    float* __restrict__ outh, float* __restrict__ outc,
    int n, int off, int cb, int leaf)
{
    __shared__ __align__(16) char lds[64 * 128];   // 64 rows x 64 bf16 (swizzled)

    const int tid   = threadIdx.x;
    const int node0 = blockIdx.x * 64;

    // staging role: thread -> (row, 8-elem k chunk)
    const int srow = tid >> 3;                 // 0..63
    const int skq  = (tid & 7) << 3;           // 0..56 step 8
    const int swby = (srow * 128 + skq * 2) ^ ((srow & 7) << 4);
    int r = node0 + srow; if (r >= n) r = n - 1;   // clamp (partial blocks)

    // compute role
    const int wv  = tid >> 6;                  // wave 0..7
    const int ln  = tid & 63;
    const int grp = ln >> 4;                   // k-group / row-group
    const int cl  = ln & 15;

    f32x4 acc[4][7] = {};

    for (int ks = 0; ks < 10; ++ks) {          // K = 640, BK = 64
        // ---- stage A tile: f32 -> bf16 into swizzled LDS ----
        {
            const int k = ks * 64 + skq;
            const float* src;
            if (k < 128) {
                src = emb + (size_t)(off + r) * 128 + k;
            } else {
                const int khm = k - 128;
                if (leaf) {
                    src = h0 + khm;
                } else {
                    const int a = khm >> 7, d0 = khm & 127;
                    src = outh + (size_t)(cb + 4 * r + a) * 128 + d0;
                }
            }
            const float4 v0 = *(const float4*)(src);
            const float4 v1 = *(const float4*)(src + 4);
            ushort8 w;
            w[0] = f2bf(v0.x); w[1] = f2bf(v0.y); w[2] = f2bf(v0.z); w[3] = f2bf(v0.w);
            w[4] = f2bf(v1.x); w[5] = f2bf(v1.y); w[6] = f2bf(v1.z); w[7] = f2bf(v1.w);
            *(ushort8*)(lds + swby) = w;
        }
        __syncthreads();

        // ---- MFMA: 2 k-chunks of 32, 4 row-frags, 7 col-frags ----
        #pragma unroll
        for (int kc = 0; kc < 2; ++kc) {
            const int kk = ks * 64 + kc * 32 + grp * 8;
            Frag8 bfr[7];
            #pragma unroll
            for (int cf = 0; cf < 7; ++cf) {
                const int col = cf * 128 + wv * 16 + cl;
                bfr[cf].u = *(const ushort8*)(Wc + (size_t)col * KIN + kk);
            }
            #pragma unroll
            for (int rf = 0; rf < 4; ++rf) {
                const int row = rf * 16 + cl;
                const unsigned rby = (unsigned)(row * 128 + kc * 64 + grp * 16) ^ ((row & 7) << 4);
                Frag8 afr; afr.u = *(const ushort8*)(lds + rby);
                #pragma unroll
                for (int cf = 0; cf < 7; ++cf)
                    acc[rf][cf] = __builtin_amdgcn_mfma_f32_16x16x32_bf16(
                        afr.b, bfr[cf].b, acc[rf][cf], 0, 0, 0);
            }
        }
        __syncthreads();
    }

    // ---- epilogue: wave-local LSTM cell ----
    const int d = wv * 16 + cl;                 // 0..127
    const float bi = b_iou[d]       + b_uiou[d];
    const float bo = b_iou[128 + d] + b_uiou[128 + d];
    const float bu = b_iou[256 + d] + b_uiou[256 + d];
    const float bwf = b_wf[d];
    float bfa[4];
    #pragma unroll
    for (int a = 0; a < 4; ++a) bfa[a] = b_uf[a * 128 + d] + bwf;

    #pragma unroll
    for (int rf = 0; rf < 4; ++rf) {
        #pragma unroll
        for (int reg = 0; reg < 4; ++reg) {
            const int m = node0 + rf * 16 + grp * 4 + reg;
            if (m < n) {
                const float i_ = acc[rf][0][reg] + bi;
                const float o_ = acc[rf][1][reg] + bo;
                const float u_ = acc[rf][2][reg] + bu;
                float c_ = sigf(i_) * tanh_fast(u_);
                #pragma unroll
                for (int a = 0; a < 4; ++a) {
                    const float fp = acc[rf][3 + a][reg] + bfa[a];
                    const float cin = leaf ? c0[a * 128 + d]
                                           : outc[(size_t)(cb + 4 * m + a) * 128 + d];
                    c_ += sigf(fp) * cin;
                }
                const float h_ = sigf(o_) * tanh_fast(c_);
                const size_t oidx = (size_t)(off + m) * 128 + d;
                outh[oidx] = h_;
                outc[oidx] = c_;
            }
        }
    }
}

extern "C" void kernel_launch(void* const* d_in, const int* in_sizes, int n_in,
                              void* d_out, int out_size, void* d_ws, size_t ws_size,
                              hipStream_t stream)
{
    const float* emb    = (const float*)d_in[0];
    const float* W_iou  = (const float*)d_in[1];
    const float* b_iou  = (const float*)d_in[2];
    const float* U_iou  = (const float*)d_in[3];
    const float* b_uiou = (const float*)d_in[4];
    const float* W_f    = (const float*)d_in[5];
    const float* b_wf   = (const float*)d_in[6];
    const float* U_f    = (const float*)d_in[7];
    const float* b_uf   = (const float*)d_in[8];
    const float* h0     = (const float*)d_in[9];
    const float* c0     = (const float*)d_in[10];

    unsigned short* Wc = (unsigned short*)d_ws;   // 896*640*2 = 1.15 MB

    hipLaunchKernelGGL(build_wc, dim3((NOUTS * KIN) / 256), dim3(256), 0, stream,
                       W_iou, U_iou, W_f, U_f, Wc);

    float* outh = (float*)d_out;
    float* outc = outh + (size_t)NNODES * 128;

    int off = 0, cb = 0;
    for (int l = DEPTH; l >= 0; --l) {
        const int n  = 1 << (2 * l);
        const int nb = (n + 63) / 64;
        hipLaunchKernelGGL(tree_level, dim3(nb), dim3(512), 0, stream,
                           emb, Wc, b_iou, b_uiou, b_wf, b_uf, h0, c0,
                           outh, outc, n, off, cb, (l == DEPTH) ? 1 : 0);
        cb = off;
        off += n;
    }
}

// Round 2
// 584.041 us; speedup vs baseline: 1.2499x; 1.2499x over previous
//
#include <hip/hip_runtime.h>
#include <hip/hip_bf16.h>

#define DEPTH   8
#define NNODES  87381   // (4^9-1)/3
#define KIN     640     // E + A*H
#define NOUTS   896     // 3H + A*H

typedef __attribute__((ext_vector_type(8))) unsigned short ushort8;
typedef __attribute__((ext_vector_type(8))) __bf16        bf16x8;
typedef __attribute__((ext_vector_type(4))) float         f32x4;

union Frag8 { ushort8 u; bf16x8 b; };

__device__ __forceinline__ unsigned short f2bf(float f) {
    unsigned int x = __float_as_uint(f);
    x += 0x7fffu + ((x >> 16) & 1u);          // round-to-nearest-even
    return (unsigned short)(x >> 16);
}
__device__ __forceinline__ float sigf(float x) {
    return __builtin_amdgcn_rcpf(1.0f + __expf(-x));
}
__device__ __forceinline__ float tanh_fast(float x) { return 2.0f * sigf(2.0f * x) - 1.0f; }

// ---------------- weight packing ----------------
// Wc[896][640] bf16 = [[W_iou | U_iou], [W_f (row d=o2&127) | U_f]]
__global__ __launch_bounds__(256) void build_wc(
    const float* __restrict__ W_iou, const float* __restrict__ U_iou,
    const float* __restrict__ W_f,   const float* __restrict__ U_f,
    unsigned short* __restrict__ Wc)
{
    int idx = blockIdx.x * 256 + threadIdx.x;
    int out = idx / KIN;
    int k   = idx - out * KIN;
    float v;
    if (out < 384) {
        v = (k < 128) ? W_iou[out * 128 + k] : U_iou[out * 512 + (k - 128)];
    } else {
        int o2 = out - 384;
        v = (k < 128) ? W_f[(o2 & 127) * 128 + k] : U_f[o2 * 512 + (k - 128)];
    }
    Wc[idx] = f2bf(v);
}

// biasc[o] = combined bias; hUc[o] = biasc[o] + (Uc . h0cat)[o]  (leaf constant)
__global__ __launch_bounds__(64) void build_consts(
    const float* __restrict__ U_iou, const float* __restrict__ U_f,
    const float* __restrict__ b_iou, const float* __restrict__ b_uiou,
    const float* __restrict__ b_wf,  const float* __restrict__ b_uf,
    const float* __restrict__ h0,
    float* __restrict__ biasc, float* __restrict__ hUc)
{
    int o = blockIdx.x * 64 + threadIdx.x;
    if (o >= NOUTS) return;
    float b = (o < 384) ? (b_iou[o] + b_uiou[o])
                        : (b_wf[(o - 384) & 127] + b_uf[o - 384]);
    const float* Urow = (o < 384) ? (U_iou + (size_t)o * 512)
                                  : (U_f + (size_t)(o - 384) * 512);
    float s = 0.f;
    #pragma unroll 4
    for (int k = 0; k < 512; k += 4) {
        float4 u = *(const float4*)(Urow + k);
        float4 h = *(const float4*)(h0 + k);
        s += u.x * h.x + u.y * h.y + u.z * h.z + u.w * h.w;
    }
    biasc[o] = b;
    hUc[o]   = b + s;
}

// ---------------- fused GEMM + LSTM cell tile (BM=64, 8 waves) ----------------
// Wave w owns output cols {c*128 + w*16 .. +15}, c = 0..6 -> epilogue wave-local.
__device__ __forceinline__ void tile_body(
    const float* __restrict__ emb,
    const unsigned short* __restrict__ Wc,
    const float* __restrict__ biasc, const float* __restrict__ hUc,
    const float* __restrict__ c0,
    float* __restrict__ outh, float* __restrict__ outc,
    char* lds,                              // 2 x 8192 B
    int n, int off, int cb, int leaf, int node0)
{
    const int tid  = threadIdx.x;
    const int srow = tid >> 3;                 // 0..63
    const int skq  = (tid & 7) << 3;           // 0..56 step 8
    const unsigned swz = (unsigned)((srow * 128 + skq * 2) ^ ((srow & 7) << 4));
    int r = node0 + srow; if (r >= n) r = n - 1;

    const int wv  = tid >> 6;
    const int ln  = tid & 63;
    const int grp = ln >> 4;
    const int cl  = ln & 15;

    const int nsteps = leaf ? 2 : 10;          // K = 128 or 640

    f32x4 acc[4][7] = {};
    float4 pv0, pv1;

    auto issue = [&](int ks) {
        const int k = ks * 64 + skq;
        const float* src;
        if (leaf || k < 128) {
            src = emb + (size_t)(off + r) * 128 + k;
        } else {
            const int khm = k - 128;
            const int a = khm >> 7, d0 = khm & 127;
            src = outh + (size_t)(cb + 4 * r + a) * 128 + d0;
        }
        pv0 = *(const float4*)(src);
        pv1 = *(const float4*)(src + 4);
    };
    auto pack_write = [&](char* buf) {
        ushort8 w;
        w[0] = f2bf(pv0.x); w[1] = f2bf(pv0.y); w[2] = f2bf(pv0.z); w[3] = f2bf(pv0.w);
        w[4] = f2bf(pv1.x); w[5] = f2bf(pv1.y); w[6] = f2bf(pv1.z); w[7] = f2bf(pv1.w);
        *(ushort8*)(buf + swz) = w;
    };

    // per-wave B column bases
    const unsigned short* wp[7];
    #pragma unroll
    for (int cf = 0; cf < 7; ++cf)
        wp[cf] = Wc + (size_t)(cf * 128 + wv * 16 + cl) * KIN;

    issue(0);
    pack_write(lds);                            // buf0
    for (int ks = 0; ks < nsteps; ++ks) {
        char* cur = lds + (size_t)(ks & 1) * 8192;
        if (ks + 1 < nsteps) issue(ks + 1);     // loads in flight across barrier+MFMA
        __syncthreads();                        // buf[ks&1] ready
        #pragma unroll
        for (int kc = 0; kc < 2; ++kc) {
            const int kk = ks * 64 + kc * 32 + grp * 8;
            Frag8 bfr[7];
            #pragma unroll
            for (int cf = 0; cf < 7; ++cf)
                bfr[cf].u = *(const ushort8*)(wp[cf] + kk);
            #pragma unroll
            for (int rf = 0; rf < 4; ++rf) {
                const int row = rf * 16 + cl;
                const unsigned rby = (unsigned)(row * 128 + kc * 64 + grp * 16) ^ ((row & 7) << 4);
                Frag8 afr; afr.u = *(const ushort8*)(cur + rby);
                #pragma unroll
                for (int cf = 0; cf < 7; ++cf)
                    acc[rf][cf] = __builtin_amdgcn_mfma_f32_16x16x32_bf16(
                        afr.b, bfr[cf].b, acc[rf][cf], 0, 0, 0);
            }
        }
        if (ks + 1 < nsteps) pack_write(lds + (size_t)((ks + 1) & 1) * 8192);
    }
    __syncthreads();                            // LDS free for caller reuse

    // ---- epilogue: wave-local LSTM cell ----
    const float* bv = leaf ? hUc : biasc;
    const int d = wv * 16 + cl;
    const float bi = bv[d];
    const float bo = bv[128 + d];
    const float bu = bv[256 + d];
    float bfa[4], cin_leaf[4];
    #pragma unroll
    for (int a = 0; a < 4; ++a) bfa[a] = bv[384 + a * 128 + d];
    if (leaf) {
        #pragma unroll
        for (int a = 0; a < 4; ++a) cin_leaf[a] = c0[a * 128 + d];
    }

    #pragma unroll
    for (int rf = 0; rf < 4; ++rf) {
        #pragma unroll
        for (int reg = 0; reg < 4; ++reg) {
            const int m = node0 + rf * 16 + grp * 4 + reg;
            if (m < n) {
                const float i_ = acc[rf][0][reg] + bi;
                const float o_ = acc[rf][1][reg] + bo;
                const float u_ = acc[rf][2][reg] + bu;
                float c_ = sigf(i_) * tanh_fast(u_);
                #pragma unroll
                for (int a = 0; a < 4; ++a) {
                    const float fp = acc[rf][3 + a][reg] + bfa[a];
                    const float cin = leaf ? cin_leaf[a]
                                           : outc[(size_t)(cb + 4 * m + a) * 128 + d];
                    c_ += sigf(fp) * cin;
                }
                const float h_ = sigf(o_) * tanh_fast(c_);
                const size_t oidx = (size_t)(off + m) * 128 + d;
                outh[oidx] = h_;
                outc[oidx] = c_;
            }
        }
    }
}

__global__ __launch_bounds__(512) void tree_level(
    const float* __restrict__ emb, const unsigned short* __restrict__ Wc,
    const float* __restrict__ biasc, const float* __restrict__ hUc,
    const float* __restrict__ c0,
    float* __restrict__ outh, float* __restrict__ outc,
    int n, int off, int cb, int leaf)
{
    __shared__ __align__(16) char lds[2 * 8192];
    tile_body(emb, Wc, biasc, hUc, c0, outh, outc, lds, n, off, cb, leaf,
              blockIdx.x * 64);
}

// levels 3..0 fused in one block (64+16+4+1 nodes)
__global__ __launch_bounds__(512) void tree_tail(
    const float* __restrict__ emb, const unsigned short* __restrict__ Wc,
    const float* __restrict__ biasc, const float* __restrict__ hUc,
    const float* __restrict__ c0,
    float* __restrict__ outh, float* __restrict__ outc,
    int off3, int cb3)
{
    __shared__ __align__(16) char lds[2 * 8192];
    int off = off3, cb = cb3;
    for (int lvl = 3; lvl >= 0; --lvl) {
        const int n = 1 << (2 * lvl);
        tile_body(emb, Wc, biasc, hUc, c0, outh, outc, lds, n, off, cb, 0, 0);
        __threadfence_block();   // make this level's global writes visible in-block
        __syncthreads();
        cb = off; off += n;
    }
}

extern "C" void kernel_launch(void* const* d_in, const int* in_sizes, int n_in,
                              void* d_out, int out_size, void* d_ws, size_t ws_size,
                              hipStream_t stream)
{
    const float* emb    = (const float*)d_in[0];
    const float* W_iou  = (const float*)d_in[1];
    const float* b_iou  = (const float*)d_in[2];
    const float* U_iou  = (const float*)d_in[3];
    const float* b_uiou = (const float*)d_in[4];
    const float* W_f    = (const float*)d_in[5];
    const float* b_wf   = (const float*)d_in[6];
    const float* U_f    = (const float*)d_in[7];
    const float* b_uf   = (const float*)d_in[8];
    const float* h0     = (const float*)d_in[9];
    const float* c0     = (const float*)d_in[10];

    unsigned short* Wc = (unsigned short*)d_ws;                   // 1,146,880 B
    float* biasc = (float*)((char*)d_ws + (size_t)NOUTS * KIN * 2);
    float* hUc   = biasc + NOUTS;

    hipLaunchKernelGGL(build_wc, dim3((NOUTS * KIN) / 256), dim3(256), 0, stream,
                       W_iou, U_iou, W_f, U_f, Wc);
    hipLaunchKernelGGL(build_consts, dim3((NOUTS + 63) / 64), dim3(64), 0, stream,
                       U_iou, U_f, b_iou, b_uiou, b_wf, b_uf, h0, biasc, hUc);

    float* outh = (float*)d_out;
    float* outc = outh + (size_t)NNODES * 128;

    // levels 8..4 as separate launches; 3..0 fused
    int off = 0, cb = 0;
    for (int l = DEPTH; l >= 4; --l) {
        const int n  = 1 << (2 * l);
        const int nb = (n + 63) / 64;
        hipLaunchKernelGGL(tree_level, dim3(nb), dim3(512), 0, stream,
                           emb, Wc, biasc, hUc, c0, outh, outc,
                           n, off, cb, (l == DEPTH) ? 1 : 0);
        cb = off;
        off += n;
    }
    hipLaunchKernelGGL(tree_tail, dim3(1), dim3(512), 0, stream,
                       emb, Wc, biasc, hUc, c0, outh, outc, off, cb);
}

// Round 3
// 423.223 us; speedup vs baseline: 1.7249x; 1.3800x over previous
//
#include <hip/hip_runtime.h>
#include <hip/hip_bf16.h>

#define DEPTH   8
#define NNODES  87381   // (4^9-1)/3
#define KIN     640     // E + A*H
#define NOUTS   896     // 3H + A*H
// fragment-major Wc: [ct=0..55][kt=0..19][lane=0..63][j=0..7]
//   element (out=ct*16+(lane&15), k=kt*32+(lane>>4)*8+j)
#define CT_STRIDE 10240   // 20*64*8
#define KT_STRIDE 512     // 64*8

typedef __attribute__((ext_vector_type(8))) unsigned short ushort8;
typedef __attribute__((ext_vector_type(8))) __bf16        bf16x8;
typedef __attribute__((ext_vector_type(4))) float         f32x4;

union Frag8 { ushort8 u; bf16x8 b; };

__device__ __forceinline__ unsigned short f2bf(float f) {
    unsigned int x = __float_as_uint(f);
    x += 0x7fffu + ((x >> 16) & 1u);          // round-to-nearest-even
    return (unsigned short)(x >> 16);
}
__device__ __forceinline__ float sigf(float x) {
    return __builtin_amdgcn_rcpf(1.0f + __expf(-x));
}
__device__ __forceinline__ float tanh_fast(float x) { return 2.0f * sigf(2.0f * x) - 1.0f; }

// ---------------- weight packing (fragment-major) ----------------
// logical Wc[896][640] = [[W_iou | U_iou], [W_f (row d=o2&127) | U_f]]
__global__ __launch_bounds__(256) void build_wc(
    const float* __restrict__ W_iou, const float* __restrict__ U_iou,
    const float* __restrict__ W_f,   const float* __restrict__ U_f,
    unsigned short* __restrict__ Wc)
{
    int idx = blockIdx.x * 256 + threadIdx.x;     // 0 .. 896*640-1
    int ct  = idx / CT_STRIDE;
    int r1  = idx - ct * CT_STRIDE;
    int kt  = r1 >> 9;
    int r2  = r1 & 511;
    int ln  = r2 >> 3;
    int j   = r2 & 7;
    int out = ct * 16 + (ln & 15);
    int k   = kt * 32 + ((ln >> 4) << 3) + j;
    float v;
    if (out < 384) {
        v = (k < 128) ? W_iou[out * 128 + k] : U_iou[(size_t)out * 512 + (k - 128)];
    } else {
        int o2 = out - 384;
        v = (k < 128) ? W_f[(o2 & 127) * 128 + k] : U_f[(size_t)o2 * 512 + (k - 128)];
    }
    Wc[idx] = f2bf(v);
}

// biasc[o] = combined bias; hUc[o] = biasc[o] + (Uc . h0cat)[o]  (leaf constant)
__global__ __launch_bounds__(64) void build_consts(
    const float* __restrict__ U_iou, const float* __restrict__ U_f,
    const float* __restrict__ b_iou, const float* __restrict__ b_uiou,
    const float* __restrict__ b_wf,  const float* __restrict__ b_uf,
    const float* __restrict__ h0,
    float* __restrict__ biasc, float* __restrict__ hUc)
{
    int o = blockIdx.x * 64 + threadIdx.x;
    if (o >= NOUTS) return;
    float b = (o < 384) ? (b_iou[o] + b_uiou[o])
                        : (b_wf[(o - 384) & 127] + b_uf[o - 384]);
    const float* Urow = (o < 384) ? (U_iou + (size_t)o * 512)
                                  : (U_f + (size_t)(o - 384) * 512);
    float s = 0.f;
    #pragma unroll 4
    for (int k = 0; k < 512; k += 4) {
        float4 u = *(const float4*)(Urow + k);
        float4 h = *(const float4*)(h0 + k);
        s += u.x * h.x + u.y * h.y + u.z * h.z + u.w * h.w;
    }
    biasc[o] = b;
    hUc[o]   = b + s;
}

// ---------------- fused GEMM + LSTM cell tile (BM=64, 8 waves) ----------------
// Wave w owns output cols {c*128 + w*16 .. +15}, c = 0..6 -> epilogue wave-local.
__device__ __forceinline__ void tile_body(
    const float* __restrict__ emb,
    const unsigned short* __restrict__ Wc,
    const float* __restrict__ biasc, const float* __restrict__ hUc,
    const float* __restrict__ c0,
    float* __restrict__ outh, float* __restrict__ outc,
    char* lds,                              // 2 x 8192 B
    int n, int off, int cb, int leaf, int node0)
{
    const int tid  = threadIdx.x;
    const int srow = tid >> 3;                 // 0..63
    const int skq  = (tid & 7) << 3;           // 0..56 step 8
    const unsigned swz = (unsigned)((srow * 128 + skq * 2) ^ ((srow & 7) << 4));
    int r = node0 + srow; if (r >= n) r = n - 1;

    const int wv  = tid >> 6;
    const int ln  = tid & 63;
    const int grp = ln >> 4;
    const int cl  = ln & 15;

    const int nsteps = leaf ? 2 : 10;          // K = 128 or 640

    f32x4 acc[4][7] = {};
    float4 pv0, pv1;

    auto issue = [&](int ks) {
        const int k = ks * 64 + skq;
        const float* src;
        if (leaf || k < 128) {
            src = emb + (size_t)(off + r) * 128 + k;
        } else {
            const int khm = k - 128;
            const int a = khm >> 7, d0 = khm & 127;
            src = outh + (size_t)(cb + 4 * r + a) * 128 + d0;
        }
        pv0 = *(const float4*)(src);
        pv1 = *(const float4*)(src + 4);
    };
    auto pack_write = [&](char* buf) {
        ushort8 w;
        w[0] = f2bf(pv0.x); w[1] = f2bf(pv0.y); w[2] = f2bf(pv0.z); w[3] = f2bf(pv0.w);
        w[4] = f2bf(pv1.x); w[5] = f2bf(pv1.y); w[6] = f2bf(pv1.z); w[7] = f2bf(pv1.w);
        *(ushort8*)(buf + swz) = w;
    };

    // per-wave B fragment bases (fragment-major layout -> coalesced 16B/lane)
    const unsigned short* wp[7];
    #pragma unroll
    for (int cf = 0; cf < 7; ++cf) {
        const int ct = cf * 8 + wv;
        wp[cf] = Wc + (size_t)ct * CT_STRIDE + (size_t)ln * 8;
    }

    issue(0);
    pack_write(lds);                            // buf0
    for (int ks = 0; ks < nsteps; ++ks) {
        char* cur = lds + (size_t)(ks & 1) * 8192;
        if (ks + 1 < nsteps) issue(ks + 1);     // loads in flight across barrier+MFMA
        __syncthreads();                        // buf[ks&1] ready
        #pragma unroll
        for (int kc = 0; kc < 2; ++kc) {
            const int kt = ks * 2 + kc;
            Frag8 bfr[7];
            #pragma unroll
            for (int cf = 0; cf < 7; ++cf)
                bfr[cf].u = *(const ushort8*)(wp[cf] + kt * KT_STRIDE);
            #pragma unroll
            for (int rf = 0; rf < 4; ++rf) {
                const int row = rf * 16 + cl;
                const unsigned rby = (unsigned)(row * 128 + kc * 64 + grp * 16) ^ ((row & 7) << 4);
                Frag8 afr; afr.u = *(const ushort8*)(cur + rby);
                #pragma unroll
                for (int cf = 0; cf < 7; ++cf)
                    acc[rf][cf] = __builtin_amdgcn_mfma_f32_16x16x32_bf16(
                        afr.b, bfr[cf].b, acc[rf][cf], 0, 0, 0);
            }
        }
        if (ks + 1 < nsteps) pack_write(lds + (size_t)((ks + 1) & 1) * 8192);
    }
    __syncthreads();                            // LDS free for caller reuse

    // ---- epilogue: wave-local LSTM cell ----
    const float* bv = leaf ? hUc : biasc;
    const int d = wv * 16 + cl;
    const float bi = bv[d];
    const float bo = bv[128 + d];
    const float bu = bv[256 + d];
    float bfa[4], cin_leaf[4];
    #pragma unroll
    for (int a = 0; a < 4; ++a) bfa[a] = bv[384 + a * 128 + d];
    if (leaf) {
        #pragma unroll
        for (int a = 0; a < 4; ++a) cin_leaf[a] = c0[a * 128 + d];
    }

    #pragma unroll
    for (int rf = 0; rf < 4; ++rf) {
        #pragma unroll
        for (int reg = 0; reg < 4; ++reg) {
            const int m = node0 + rf * 16 + grp * 4 + reg;
            if (m < n) {
                const float i_ = acc[rf][0][reg] + bi;
                const float o_ = acc[rf][1][reg] + bo;
                const float u_ = acc[rf][2][reg] + bu;
                float c_ = sigf(i_) * tanh_fast(u_);
                #pragma unroll
                for (int a = 0; a < 4; ++a) {
                    const float fp = acc[rf][3 + a][reg] + bfa[a];
                    const float cin = leaf ? cin_leaf[a]
                                           : outc[(size_t)(cb + 4 * m + a) * 128 + d];
                    c_ += sigf(fp) * cin;
                }
                const float h_ = sigf(o_) * tanh_fast(c_);
                const size_t oidx = (size_t)(off + m) * 128 + d;
                outh[oidx] = h_;
                outc[oidx] = c_;
            }
        }
    }
}

__global__ __launch_bounds__(512) void tree_level(
    const float* __restrict__ emb, const unsigned short* __restrict__ Wc,
    const float* __restrict__ biasc, const float* __restrict__ hUc,
    const float* __restrict__ c0,
    float* __restrict__ outh, float* __restrict__ outc,
    int n, int off, int cb, int leaf)
{
    __shared__ __align__(16) char lds[2 * 8192];
    tile_body(emb, Wc, biasc, hUc, c0, outh, outc, lds, n, off, cb, leaf,
              blockIdx.x * 64);
}

// levels 3..0 fused in one block (64+16+4+1 nodes)
__global__ __launch_bounds__(512) void tree_tail(
    const float* __restrict__ emb, const unsigned short* __restrict__ Wc,
    const float* __restrict__ biasc, const float* __restrict__ hUc,
    const float* __restrict__ c0,
    float* __restrict__ outh, float* __restrict__ outc,
    int off3, int cb3)
{
    __shared__ __align__(16) char lds[2 * 8192];
    int off = off3, cb = cb3;
    for (int lvl = 3; lvl >= 0; --lvl) {
        const int n = 1 << (2 * lvl);
        tile_body(emb, Wc, biasc, hUc, c0, outh, outc, lds, n, off, cb, 0, 0);
        __threadfence_block();   // make this level's global writes visible in-block
        __syncthreads();
        cb = off; off += n;
    }
}

extern "C" void kernel_launch(void* const* d_in, const int* in_sizes, int n_in,
                              void* d_out, int out_size, void* d_ws, size_t ws_size,
                              hipStream_t stream)
{
    const float* emb    = (const float*)d_in[0];
    const float* W_iou  = (const float*)d_in[1];
    const float* b_iou  = (const float*)d_in[2];
    const float* U_iou  = (const float*)d_in[3];
    const float* b_uiou = (const float*)d_in[4];
    const float* W_f    = (const float*)d_in[5];
    const float* b_wf   = (const float*)d_in[6];
    const float* U_f    = (const float*)d_in[7];
    const float* b_uf   = (const float*)d_in[8];
    const float* h0     = (const float*)d_in[9];
    const float* c0     = (const float*)d_in[10];

    unsigned short* Wc = (unsigned short*)d_ws;                   // 1,146,880 B
    float* biasc = (float*)((char*)d_ws + (size_t)NOUTS * KIN * 2);
    float* hUc   = biasc + NOUTS;

    hipLaunchKernelGGL(build_wc, dim3((NOUTS * KIN) / 256), dim3(256), 0, stream,
                       W_iou, U_iou, W_f, U_f, Wc);
    hipLaunchKernelGGL(build_consts, dim3((NOUTS + 63) / 64), dim3(64), 0, stream,
                       U_iou, U_f, b_iou, b_uiou, b_wf, b_uf, h0, biasc, hUc);

    float* outh = (float*)d_out;
    float* outc = outh + (size_t)NNODES * 128;

    // levels 8..4 as separate launches; 3..0 fused
    int off = 0, cb = 0;
    for (int l = DEPTH; l >= 4; --l) {
        const int n  = 1 << (2 * l);
        const int nb = (n + 63) / 64;
        hipLaunchKernelGGL(tree_level, dim3(nb), dim3(512), 0, stream,
                           emb, Wc, biasc, hUc, c0, outh, outc,
                           n, off, cb, (l == DEPTH) ? 1 : 0);
        cb = off;
        off += n;
    }
    hipLaunchKernelGGL(tree_tail, dim3(1), dim3(512), 0, stream,
                       emb, Wc, biasc, hUc, c0, outh, outc, off, cb);
}

// Round 4
// 279.567 us; speedup vs baseline: 2.6112x; 1.5139x over previous
//
#include <hip/hip_runtime.h>
#include <hip/hip_bf16.h>

#define DEPTH   8
#define NNODES  87381   // (4^9-1)/3
#define KIN     640     // E + A*H
#define NOUTS   896     // 3H + A*H
// fragment-major Wc: [ct=0..55][kt=0..19][lane=0..63][j=0..7]
//   element (out=ct*16+(lane&15), k=kt*32+(lane>>4)*8+j)
#define CT_STRIDE 10240   // 20*64*8
#define KT_STRIDE 512     // 64*8

typedef __attribute__((ext_vector_type(8))) unsigned short ushort8;
typedef __attribute__((ext_vector_type(4))) unsigned short ushort4v;
typedef __attribute__((ext_vector_type(8))) __bf16        bf16x8;
typedef __attribute__((ext_vector_type(4))) float         f32x4;

union Frag8 { ushort8 u; bf16x8 b; };

__device__ __forceinline__ unsigned short f2bf(float f) {
    unsigned int x = __float_as_uint(f);
    x += 0x7fffu + ((x >> 16) & 1u);          // round-to-nearest-even
    return (unsigned short)(x >> 16);
}
__device__ __forceinline__ float sigf(float x) {
    return __builtin_amdgcn_rcpf(1.0f + __expf(-x));
}
__device__ __forceinline__ float tanh_fast(float x) { return 2.0f * sigf(2.0f * x) - 1.0f; }

// ---------------- weight packing (fragment-major) ----------------
// logical Wc[896][640] = [[W_iou | U_iou], [W_f (row d=o2&127) | U_f]]
__global__ __launch_bounds__(256) void build_wc(
    const float* __restrict__ W_iou, const float* __restrict__ U_iou,
    const float* __restrict__ W_f,   const float* __restrict__ U_f,
    unsigned short* __restrict__ Wc)
{
    int idx = blockIdx.x * 256 + threadIdx.x;     // 0 .. 896*640-1
    int ct  = idx / CT_STRIDE;
    int r1  = idx - ct * CT_STRIDE;
    int kt  = r1 >> 9;
    int r2  = r1 & 511;
    int ln  = r2 >> 3;
    int j   = r2 & 7;
    int out = ct * 16 + (ln & 15);
    int k   = kt * 32 + ((ln >> 4) << 3) + j;
    float v;
    if (out < 384) {
        v = (k < 128) ? W_iou[out * 128 + k] : U_iou[(size_t)out * 512 + (k - 128)];
    } else {
        int o2 = out - 384;
        v = (k < 128) ? W_f[(o2 & 127) * 128 + k] : U_f[(size_t)o2 * 512 + (k - 128)];
    }
    Wc[idx] = f2bf(v);
}

// biasc[o] = combined bias; hUc[o] = biasc[o] + (Uc . h0cat)[o]  (leaf constant)
__global__ __launch_bounds__(64) void build_consts(
    const float* __restrict__ U_iou, const float* __restrict__ U_f,
    const float* __restrict__ b_iou, const float* __restrict__ b_uiou,
    const float* __restrict__ b_wf,  const float* __restrict__ b_uf,
    const float* __restrict__ h0,
    float* __restrict__ biasc, float* __restrict__ hUc)
{
    int o = blockIdx.x * 64 + threadIdx.x;
    if (o >= NOUTS) return;
    float b = (o < 384) ? (b_iou[o] + b_uiou[o])
                        : (b_wf[(o - 384) & 127] + b_uf[o - 384]);
    const float* Urow = (o < 384) ? (U_iou + (size_t)o * 512)
                                  : (U_f + (size_t)(o - 384) * 512);
    float s0 = 0.f, s1 = 0.f, s2 = 0.f, s3 = 0.f;
    #pragma unroll 2
    for (int k = 0; k < 512; k += 16) {
        float4 u0 = *(const float4*)(Urow + k);
        float4 h0v = *(const float4*)(h0 + k);
        float4 u1 = *(const float4*)(Urow + k + 4);
        float4 h1v = *(const float4*)(h0 + k + 4);
        float4 u2 = *(const float4*)(Urow + k + 8);
        float4 h2v = *(const float4*)(h0 + k + 8);
        float4 u3 = *(const float4*)(Urow + k + 12);
        float4 h3v = *(const float4*)(h0 + k + 12);
        s0 += u0.x*h0v.x + u0.y*h0v.y + u0.z*h0v.z + u0.w*h0v.w;
        s1 += u1.x*h1v.x + u1.y*h1v.y + u1.z*h1v.z + u1.w*h1v.w;
        s2 += u2.x*h2v.x + u2.y*h2v.y + u2.z*h2v.z + u2.w*h2v.w;
        s3 += u3.x*h3v.x + u3.y*h3v.y + u3.z*h3v.z + u3.w*h3v.w;
    }
    biasc[o] = b;
    hUc[o]   = b + ((s0 + s1) + (s2 + s3));
}

// ---------------- big-level kernel (levels 8,7): BM=64, full-N per block ----
// Wave w owns output cols {c*128 + w*16 .. +15}, c = 0..6 -> epilogue wave-local.
__device__ __forceinline__ void tile_body(
    const float* __restrict__ emb,
    const unsigned short* __restrict__ Wc,
    const float* __restrict__ biasc, const float* __restrict__ hUc,
    const float* __restrict__ c0,
    float* __restrict__ outh, float* __restrict__ outc,
    char* lds,                              // 2 x 8192 B
    int n, int off, int cb, int leaf, int node0)
{
    const int tid  = threadIdx.x;
    const int srow = tid >> 3;                 // 0..63
    const int skq  = (tid & 7) << 3;           // 0..56 step 8
    const unsigned swz = (unsigned)((srow * 128 + skq * 2) ^ ((srow & 7) << 4));
    int r = node0 + srow; if (r >= n) r = n - 1;

    const int wv  = tid >> 6;
    const int ln  = tid & 63;
    const int grp = ln >> 4;
    const int cl  = ln & 15;

    const int nsteps = leaf ? 2 : 10;          // K = 128 or 640

    f32x4 acc[4][7] = {};
    float4 pv0, pv1;

    auto issue = [&](int ks) {
        const int k = ks * 64 + skq;
        const float* src;
        if (leaf || k < 128) {
            src = emb + (size_t)(off + r) * 128 + k;
        } else {
            const int khm = k - 128;
            const int a = khm >> 7, d0 = khm & 127;
            src = outh + (size_t)(cb + 4 * r + a) * 128 + d0;
        }
        pv0 = *(const float4*)(src);
        pv1 = *(const float4*)(src + 4);
    };
    auto pack_write = [&](char* buf) {
        ushort8 w;
        w[0] = f2bf(pv0.x); w[1] = f2bf(pv0.y); w[2] = f2bf(pv0.z); w[3] = f2bf(pv0.w);
        w[4] = f2bf(pv1.x); w[5] = f2bf(pv1.y); w[6] = f2bf(pv1.z); w[7] = f2bf(pv1.w);
        *(ushort8*)(buf + swz) = w;
    };

    // per-wave B fragment bases (fragment-major layout -> coalesced 16B/lane)
    const unsigned short* wp[7];
    #pragma unroll
    for (int cf = 0; cf < 7; ++cf) {
        const int ct = cf * 8 + wv;
        wp[cf] = Wc + (size_t)ct * CT_STRIDE + (size_t)ln * 8;
    }

    issue(0);
    pack_write(lds);                            // buf0
    for (int ks = 0; ks < nsteps; ++ks) {
        char* cur = lds + (size_t)(ks & 1) * 8192;
        if (ks + 1 < nsteps) issue(ks + 1);     // loads in flight across barrier+MFMA
        __syncthreads();                        // buf[ks&1] ready
        #pragma unroll
        for (int kc = 0; kc < 2; ++kc) {
            const int kt = ks * 2 + kc;
            Frag8 bfr[7];
            #pragma unroll
            for (int cf = 0; cf < 7; ++cf)
                bfr[cf].u = *(const ushort8*)(wp[cf] + kt * KT_STRIDE);
            #pragma unroll
            for (int rf = 0; rf < 4; ++rf) {
                const int row = rf * 16 + cl;
                const unsigned rby = (unsigned)(row * 128 + kc * 64 + grp * 16) ^ ((row & 7) << 4);
                Frag8 afr; afr.u = *(const ushort8*)(cur + rby);
                #pragma unroll
                for (int cf = 0; cf < 7; ++cf)
                    acc[rf][cf] = __builtin_amdgcn_mfma_f32_16x16x32_bf16(
                        afr.b, bfr[cf].b, acc[rf][cf], 0, 0, 0);
            }
        }
        if (ks + 1 < nsteps) pack_write(lds + (size_t)((ks + 1) & 1) * 8192);
    }
    __syncthreads();

    // ---- epilogue: wave-local LSTM cell ----
    const float* bv = leaf ? hUc : biasc;
    const int d = wv * 16 + cl;
    const float bi = bv[d];
    const float bo = bv[128 + d];
    const float bu = bv[256 + d];
    float bfa[4], cin_leaf[4];
    #pragma unroll
    for (int a = 0; a < 4; ++a) bfa[a] = bv[384 + a * 128 + d];
    if (leaf) {
        #pragma unroll
        for (int a = 0; a < 4; ++a) cin_leaf[a] = c0[a * 128 + d];
    }

    #pragma unroll
    for (int rf = 0; rf < 4; ++rf) {
        #pragma unroll
        for (int reg = 0; reg < 4; ++reg) {
            const int m = node0 + rf * 16 + grp * 4 + reg;
            if (m < n) {
                const float i_ = acc[rf][0][reg] + bi;
                const float o_ = acc[rf][1][reg] + bo;
                const float u_ = acc[rf][2][reg] + bu;
                float c_ = sigf(i_) * tanh_fast(u_);
                #pragma unroll
                for (int a = 0; a < 4; ++a) {
                    const float fp = acc[rf][3 + a][reg] + bfa[a];
                    const float cin = leaf ? cin_leaf[a]
                                           : outc[(size_t)(cb + 4 * m + a) * 128 + d];
                    c_ += sigf(fp) * cin;
                }
                const float h_ = sigf(o_) * tanh_fast(c_);
                const size_t oidx = (size_t)(off + m) * 128 + d;
                outh[oidx] = h_;
                outc[oidx] = c_;
            }
        }
    }
}

__global__ __launch_bounds__(512) void tree_level(
    const float* __restrict__ emb, const unsigned short* __restrict__ Wc,
    const float* __restrict__ biasc, const float* __restrict__ hUc,
    const float* __restrict__ c0,
    float* __restrict__ outh, float* __restrict__ outc,
    int n, int off, int cb, int leaf)
{
    __shared__ __align__(16) char lds[2 * 8192];
    tile_body(emb, Wc, biasc, hUc, c0, outh, outc, lds, n, off, cb, leaf,
              blockIdx.x * 64);
}

// ---------------- small-level kernel (levels 6..0): d-split + split-K --------
// Block (mt,dg): rows [mt*32, mt*32+32), cols d in [dg*16, dg*16+16) and the 7
// coupled col-frags ct = cf*8+dg. Full A-panel staged to LDS once (no K-loop
// barriers); 8 waves = (rf in 2) x (kquarter in 4), LDS cross-wave reduction.
__global__ __launch_bounds__(512) void tree_dsplit(
    const float* __restrict__ emb, const unsigned short* __restrict__ Wc,
    const float* __restrict__ biasc,
    float* __restrict__ outh, float* __restrict__ outc,
    int n, int off, int cb)
{
    __shared__ __align__(16) char lds[57344];  // panel 40960 B; reduction reuses 57344 B

    const int tid   = threadIdx.x;
    const int mt    = blockIdx.x >> 3;
    const int dg    = blockIdx.x & 7;
    const int node0 = mt * 32;

    // ---- stage A-panel [32 rows][640 k] bf16 (10 stripes x 32x64, swizzled) ----
    {
        const int srow = tid >> 4;              // 0..31
        const int sc4  = (tid & 15) << 2;       // 0..60 step 4
        int r = node0 + srow; if (r >= n) r = n - 1;
        const unsigned wby = (unsigned)((srow * 128 + sc4 * 2) ^ ((srow & 7) << 4));
        float4 v[10];
        #pragma unroll
        for (int i = 0; i < 10; ++i) {
            const int k = i * 64 + sc4;
            const float* src = (k < 128)
                ? (emb + (size_t)(off + r) * 128 + k)
                : (outh + (size_t)(cb + 4 * r + ((k - 128) >> 7)) * 128 + ((k - 128) & 127));
            v[i] = *(const float4*)src;
        }
        #pragma unroll
        for (int i = 0; i < 10; ++i) {
            ushort4v w;
            w[0] = f2bf(v[i].x); w[1] = f2bf(v[i].y);
            w[2] = f2bf(v[i].z); w[3] = f2bf(v[i].w);
            *(ushort4v*)(lds + i * 4096 + wby) = w;
        }
    }
    __syncthreads();

    // ---- barrier-free K-loop: wave = (rf, kq), 5 kt each ----
    const int wv  = tid >> 6;
    const int ln  = tid & 63;
    const int grp = ln >> 4;
    const int cl  = ln & 15;
    const int rf  = wv & 1;
    const int kq  = wv >> 1;
    const int row = rf * 16 + cl;
    const int swr = (row & 7) << 4;

    const unsigned short* wp[7];
    #pragma unroll
    for (int cf = 0; cf < 7; ++cf)
        wp[cf] = Wc + (size_t)(cf * 8 + dg) * CT_STRIDE + (size_t)ln * 8;

    f32x4 acc[7] = {};
    #pragma unroll
    for (int t = 0; t < 5; ++t) {
        const int kt = kq * 5 + t;
        Frag8 afr;
        afr.u = *(const ushort8*)(lds + (kt >> 1) * 4096 + row * 128
                                  + (((kt & 1) * 64 + grp * 16) ^ swr));
        Frag8 bfr[7];
        #pragma unroll
        for (int cf = 0; cf < 7; ++cf)
            bfr[cf].u = *(const ushort8*)(wp[cf] + (size_t)kt * KT_STRIDE);
        #pragma unroll
        for (int cf = 0; cf < 7; ++cf)
            acc[cf] = __builtin_amdgcn_mfma_f32_16x16x32_bf16(
                afr.b, bfr[cf].b, acc[cf], 0, 0, 0);
    }
    __syncthreads();                            // panel dead; LDS reused below

    // ---- cross-wave K reduction ----
    float* red = (float*)lds;
    const int slot = ((kq * 2 + rf) * 64 + ln) * 28;   // 7 x f32x4 per (wave,lane)
    if (kq != 0) {
        #pragma unroll
        for (int cf = 0; cf < 7; ++cf)
            *(f32x4*)(red + slot + cf * 4) = acc[cf];
    }
    __syncthreads();
    if (kq == 0) {
        #pragma unroll
        for (int q = 1; q < 4; ++q) {
            const int s2 = ((q * 2 + rf) * 64 + ln) * 28;
            #pragma unroll
            for (int cf = 0; cf < 7; ++cf)
                acc[cf] += *(const f32x4*)(red + s2 + cf * 4);
        }

        // ---- epilogue (waves 0,1 only) ----
        const int d = dg * 16 + cl;
        const float bi = biasc[d];
        const float bo = biasc[128 + d];
        const float bu = biasc[256 + d];
        float bfa[4];
        #pragma unroll
        for (int a = 0; a < 4; ++a) bfa[a] = biasc[384 + a * 128 + d];

        #pragma unroll
        for (int reg = 0; reg < 4; ++reg) {
            const int m = node0 + rf * 16 + grp * 4 + reg;
            if (m < n) {
                const float i_ = acc[0][reg] + bi;
                const float o_ = acc[1][reg] + bo;
                const float u_ = acc[2][reg] + bu;
                float c_ = sigf(i_) * tanh_fast(u_);
                #pragma unroll
                for (int a = 0; a < 4; ++a) {
                    const float fp = acc[3 + a][reg] + bfa[a];
                    const float cin = outc[(size_t)(cb + 4 * m + a) * 128 + d];
                    c_ += sigf(fp) * cin;
                }
                const float h_ = sigf(o_) * tanh_fast(c_);
                const size_t oidx = (size_t)(off + m) * 128 + d;
                outh[oidx] = h_;
                outc[oidx] = c_;
            }
        }
    }
}

extern "C" void kernel_launch(void* const* d_in, const int* in_sizes, int n_in,
                              void* d_out, int out_size, void* d_ws, size_t ws_size,
                              hipStream_t stream)
{
    const float* emb    = (const float*)d_in[0];
    const float* W_iou  = (const float*)d_in[1];
    const float* b_iou  = (const float*)d_in[2];
    const float* U_iou  = (const float*)d_in[3];
    const float* b_uiou = (const float*)d_in[4];
    const float* W_f    = (const float*)d_in[5];
    const float* b_wf   = (const float*)d_in[6];
    const float* U_f    = (const float*)d_in[7];
    const float* b_uf   = (const float*)d_in[8];
    const float* h0     = (const float*)d_in[9];
    const float* c0     = (const float*)d_in[10];

    unsigned short* Wc = (unsigned short*)d_ws;                   // 1,146,880 B
    float* biasc = (float*)((char*)d_ws + (size_t)NOUTS * KIN * 2);
    float* hUc   = biasc + NOUTS;

    hipLaunchKernelGGL(build_wc, dim3((NOUTS * KIN) / 256), dim3(256), 0, stream,
                       W_iou, U_iou, W_f, U_f, Wc);
    hipLaunchKernelGGL(build_consts, dim3((NOUTS + 63) / 64), dim3(64), 0, stream,
                       U_iou, U_f, b_iou, b_uiou, b_wf, b_uf, h0, biasc, hUc);

    float* outh = (float*)d_out;
    float* outc = outh + (size_t)NNODES * 128;

    int off = 0, cb = 0;
    for (int l = DEPTH; l >= 0; --l) {
        const int n = 1 << (2 * l);
        if (l >= DEPTH - 1) {
            const int nb = (n + 63) / 64;
            hipLaunchKernelGGL(tree_level, dim3(nb), dim3(512), 0, stream,
                               emb, Wc, biasc, hUc, c0, outh, outc,
                               n, off, cb, (l == DEPTH) ? 1 : 0);
        } else {
            const int nb = ((n + 31) / 32) * 8;
            hipLaunchKernelGGL(tree_dsplit, dim3(nb), dim3(512), 0, stream,
                               emb, Wc, biasc, outh, outc, n, off, cb);
        }
        cb = off;
        off += n;
    }
}